// Round 6
// baseline (119.850 us; speedup 1.0000x reference)
//
#include <hip/hip_runtime.h>
#include <hip/hip_bf16.h>
#include <stdint.h>

#define B_SZ 4
#define T_SEQ 1024
#define E_DIM 1024
#define NH 16
#define HD 64
#define THREE_E 3072
#define NTOK 4096

typedef unsigned short u16;
typedef unsigned int u32;
using short8v = __attribute__((ext_vector_type(8))) short;
using f32x4 = __attribute__((ext_vector_type(4))) float;

__device__ __forceinline__ u16 f2bf(float f) {
    union { float f; uint32_t u; } c; c.f = f;
    uint32_t u = c.u;
    uint32_t r = (u + 0x7FFFu + ((u >> 16) & 1u)) >> 16;
    return (u16)r;
}

__device__ __forceinline__ u32 cvt_pk_bf16(float lo, float hi) {
    u32 r;
    asm("v_cvt_pk_bf16_f32 %0, %1, %2" : "=v"(r) : "v"(lo), "v"(hi));
    return r;
}

__device__ __forceinline__ void gload_lds16(const u16* g, u16* l) {
    __builtin_amdgcn_global_load_lds((const __attribute__((address_space(1))) void*)g,
                                     (__attribute__((address_space(3))) void*)l, 16, 0, 0);
}

// ---------------- RMSNorm: x[4096][1024] f32 -> bf16
__global__ __launch_bounds__(256) void rmsnorm_kernel(const float* __restrict__ x,
                                                      const float* __restrict__ scale,
                                                      u16* __restrict__ xn) {
    int row = blockIdx.x;
    int tid = threadIdx.x;
    const float4* xr = reinterpret_cast<const float4*>(x + (size_t)row * E_DIM);
    float4 v = xr[tid];
    float ss = v.x * v.x + v.y * v.y + v.z * v.z + v.w * v.w;
    for (int off = 32; off > 0; off >>= 1) ss += __shfl_xor(ss, off);
    __shared__ float red[4];
    if ((tid & 63) == 0) red[tid >> 6] = ss;
    __syncthreads();
    float total = red[0] + red[1] + red[2] + red[3];
    float rs = rsqrtf(total * (1.0f / E_DIM) + 1e-5f);
    const float4* sc4 = reinterpret_cast<const float4*>(scale);
    float4 s = sc4[tid];
    u16* o = xn + (size_t)row * E_DIM + tid * 4;
    o[0] = f2bf(v.x * rs * s.x);
    o[1] = f2bf(v.y * rs * s.y);
    o[2] = f2bf(v.z * rs * s.z);
    o[3] = f2bf(v.w * rs * s.w);
}

// ---------------- weight f32 -> bf16 cast
__global__ __launch_bounds__(256) void cast_weights_kernel(const float* __restrict__ wq,
                                                           const float* __restrict__ wp,
                                                           u16* __restrict__ wqb,
                                                           u16* __restrict__ wpb) {
    const int NQ = (THREE_E * E_DIM) / 4;
    const int NP = (E_DIM * E_DIM) / 4;
    int i = blockIdx.x * 256 + threadIdx.x;
    if (i < NQ) {
        float4 v = reinterpret_cast<const float4*>(wq)[i];
        u16* o = wqb + (size_t)i * 4;
        o[0] = f2bf(v.x); o[1] = f2bf(v.y); o[2] = f2bf(v.z); o[3] = f2bf(v.w);
    } else if (i < NQ + NP) {
        int j = i - NQ;
        float4 v = reinterpret_cast<const float4*>(wp)[j];
        u16* o = wpb + (size_t)j * 4;
        o[0] = f2bf(v.x); o[1] = f2bf(v.y); o[2] = f2bf(v.z); o[3] = f2bf(v.w);
    }
}

// ================= 256x192 4-phase GEMM (T2+T3+T4+T5), BK=64, 8 waves ================
// C[m][n] = sum_k A[m][k]*Bw[n][k]. Grid (N/192, M/256) = 16x16 = 256 blocks (full CU
// coverage). Per phase: {ds_read subtile || stage -> barrier -> lgkm(0) -> 12 MFMA ->
// barrier}; counted vmcnt(7) once per K-step; stages target only regions whose reads
// completed a barrier earlier (race-free). Chunk XOR swizzle on both sides (rule #21).
#define MFMA12(AF, BF, MO)                                                      \
    do {                                                                        \
        _Pragma("unroll") for (int mi_ = 0; mi_ < 4; ++mi_)                     \
            _Pragma("unroll") for (int ni_ = 0; ni_ < 3; ++ni_)                 \
                acc[(MO) + mi_][ni_] = __builtin_amdgcn_mfma_f32_16x16x32_bf16( \
                    (AF)[mi_], (BF)[ni_], acc[(MO) + mi_][ni_], 0, 0, 0);       \
    } while (0)

template <int K>
__global__ __launch_bounds__(512, 2) void gemm8_kernel(const u16* __restrict__ A,
                                                       const u16* __restrict__ Bw,
                                                       u16* __restrict__ C, int N) {
    constexpr int NT = K / 64;
    __shared__ __align__(16) u16 As[2][256 * 64];   // 64 KB
    __shared__ __align__(16) u16 Bs[2][192 * 64];   // 48 KB
    int tid = threadIdx.x;
    int lane = tid & 63, wid = tid >> 6;
    int lq = lane & 15, lg = lane >> 4;
    int wm = wid >> 2, wn = wid & 3;
    int mblk = blockIdx.y * 256, nblk = blockIdx.x * 192;

    // staging: instr s covers 64 rows; thread -> row s*64+(tid>>3), dest chunk tid&7;
    // pre-swizzled source chunk = (tid&7) ^ (row&7).
    int srow = tid >> 3, schunk = tid & 7;
    int csw = (schunk ^ (srow & 7)) * 8;
    const u16* gA0 = A + (size_t)(mblk + srow) * K + csw;
    const u16* gB0 = Bw + (size_t)(nblk + srow) * K + csw;
    int dst = srow * 64 + schunk * 8;   // + s*4096 per instr

    // ds_read: frag (mi,kk): row=arow+mi*16, stored chunk (kk*4+lg)^(lq&7)
    int arow = wm * 128 + lq;
    int brow = wn * 48 + lq;
    int r7 = lq & 7;
    int co0 = ((0 + lg) ^ r7) * 8;
    int co1 = ((4 + lg) ^ r7) * 8;

    f32x4 acc[8][3] = {};

    // prologue: t0 -> buf0 (7 loads), t1 -> buf1 (7 loads), wait t0
#pragma unroll
    for (int s = 0; s < 3; ++s) gload_lds16(gB0 + (size_t)s * 64 * K, &Bs[0][s * 4096 + dst]);
#pragma unroll
    for (int s = 0; s < 4; ++s) gload_lds16(gA0 + (size_t)s * 64 * K, &As[0][s * 4096 + dst]);
#pragma unroll
    for (int s = 0; s < 3; ++s) gload_lds16(gB0 + (size_t)s * 64 * K + 64, &Bs[1][s * 4096 + dst]);
#pragma unroll
    for (int s = 0; s < 4; ++s) gload_lds16(gA0 + (size_t)s * 64 * K + 64, &As[1][s * 4096 + dst]);
    asm volatile("s_waitcnt vmcnt(7)" ::: "memory");
    __builtin_amdgcn_s_barrier();

    for (int t = 0; t < NT; ++t) {
        const int buf = t & 1;
        const u16* Ab = As[buf];
        const u16* Bb = Bs[buf];
        const bool pre = (t + 2 < NT);
        short8v a0[4], a1[4], a2[4], a3[4], b0[3], b1[3];
        // ---- P1: reads A m0-3 kk0 + B kk0
#pragma unroll
        for (int mi = 0; mi < 4; ++mi)
            a0[mi] = *reinterpret_cast<const short8v*>(Ab + (arow + mi * 16) * 64 + co0);
#pragma unroll
        for (int ni = 0; ni < 3; ++ni)
            b0[ni] = *reinterpret_cast<const short8v*>(Bb + (brow + ni * 16) * 64 + co0);
        __builtin_amdgcn_s_barrier();
        asm volatile("s_waitcnt lgkmcnt(0)" ::: "memory");
        __builtin_amdgcn_sched_barrier(0);
        __builtin_amdgcn_s_setprio(1);
        MFMA12(a0, b0, 0);
        __builtin_amdgcn_s_setprio(0);
        __builtin_amdgcn_s_barrier();
        // ---- P2: reads A m0-3 kk1 + B kk1
#pragma unroll
        for (int mi = 0; mi < 4; ++mi)
            a1[mi] = *reinterpret_cast<const short8v*>(Ab + (arow + mi * 16) * 64 + co1);
#pragma unroll
        for (int ni = 0; ni < 3; ++ni)
            b1[ni] = *reinterpret_cast<const short8v*>(Bb + (brow + ni * 16) * 64 + co1);
        __builtin_amdgcn_s_barrier();
        asm volatile("s_waitcnt lgkmcnt(0)" ::: "memory");
        __builtin_amdgcn_sched_barrier(0);
        __builtin_amdgcn_s_setprio(1);
        MFMA12(a1, b1, 0);
        __builtin_amdgcn_s_setprio(0);
        __builtin_amdgcn_s_barrier();
        // ---- P3: reads A m4-7 kk0+kk1; stage B(t+2) (B of tile t fully read in P1+P2)
#pragma unroll
        for (int mi = 0; mi < 4; ++mi) {
            a2[mi] = *reinterpret_cast<const short8v*>(Ab + (arow + 64 + mi * 16) * 64 + co0);
            a3[mi] = *reinterpret_cast<const short8v*>(Ab + (arow + 64 + mi * 16) * 64 + co1);
        }
        if (pre) {
#pragma unroll
            for (int s = 0; s < 3; ++s)
                gload_lds16(gB0 + (size_t)s * 64 * K + (t + 2) * 64, &Bs[buf][s * 4096 + dst]);
        }
        __builtin_amdgcn_s_barrier();
        asm volatile("s_waitcnt lgkmcnt(0)" ::: "memory");
        __builtin_amdgcn_sched_barrier(0);
        __builtin_amdgcn_s_setprio(1);
        MFMA12(a2, b0, 4);
        __builtin_amdgcn_s_setprio(0);
        __builtin_amdgcn_s_barrier();
        // ---- P4: stage A(t+2) (A of tile t fully read by end P3); counted vmcnt
        if (pre) {
#pragma unroll
            for (int s = 0; s < 4; ++s)
                gload_lds16(gA0 + (size_t)s * 64 * K + (t + 2) * 64, &As[buf][s * 4096 + dst]);
            asm volatile("s_waitcnt vmcnt(7)" ::: "memory");
        } else {
            asm volatile("s_waitcnt vmcnt(0)" ::: "memory");
        }
        __builtin_amdgcn_s_barrier();
        __builtin_amdgcn_s_setprio(1);
        MFMA12(a3, b1, 4);
        __builtin_amdgcn_s_setprio(0);
        __builtin_amdgcn_s_barrier();
    }
    // epilogue
#pragma unroll
    for (int mi = 0; mi < 8; ++mi) {
#pragma unroll
        for (int ni = 0; ni < 3; ++ni) {
#pragma unroll
            for (int j = 0; j < 4; ++j) {
                int row = mblk + wm * 128 + mi * 16 + lg * 4 + j;
                int col = nblk + wn * 48 + ni * 16 + lq;
                C[(size_t)row * N + col] = f2bf(acc[mi][ni][j]);
            }
        }
    }
}

// ---------------- GEMM m97-structure (out-proj: N=1024 not divisible by 192)
template <bool OUT_BF16>
__global__ __launch_bounds__(256) void gemm_lds_kernel(const u16* __restrict__ A,
                                                       const u16* __restrict__ Bw,
                                                       void* __restrict__ C,
                                                       int N, int K) {
    __shared__ u16 As[128 * 32];
    __shared__ u16 Bs[128 * 32];
    int tid = threadIdx.x;
    int lane = tid & 63, wid = tid >> 6;
    int lq = lane & 15, lg = lane >> 4;
    int mblk = blockIdx.y * 128, nblk = blockIdx.x * 128;

    int srow = wid * 32 + (lane >> 2);
    int scol = (lane & 3) * 8;
    const u16* gA = A + (size_t)(mblk + srow) * K + scol;
    const u16* gB = Bw + (size_t)(nblk + srow) * K + scol;
    u16* lA = As + wid * 1024;
    u16* lB = Bs + wid * 1024;

    f32x4 acc[4][4] = {};
    int m0w = (wid >> 1) * 64;
    int n0w = (wid & 1) * 64;

    for (int k0 = 0; k0 < K; k0 += 32) {
        __syncthreads();
        gload_lds16(gA + k0, lA);
        gload_lds16(gA + k0 + (size_t)16 * K, lA + 512);
        gload_lds16(gB + k0, lB);
        gload_lds16(gB + k0 + (size_t)16 * K, lB + 512);
        __syncthreads();
        short8v af[4], bf[4];
#pragma unroll
        for (int mi = 0; mi < 4; ++mi)
            af[mi] = *reinterpret_cast<const short8v*>(&As[(m0w + mi * 16 + lq) * 32 + lg * 8]);
#pragma unroll
        for (int ni = 0; ni < 4; ++ni)
            bf[ni] = *reinterpret_cast<const short8v*>(&Bs[(n0w + ni * 16 + lq) * 32 + lg * 8]);
#pragma unroll
        for (int mi = 0; mi < 4; ++mi)
#pragma unroll
            for (int ni = 0; ni < 4; ++ni)
                acc[mi][ni] = __builtin_amdgcn_mfma_f32_16x16x32_bf16(af[mi], bf[ni], acc[mi][ni], 0, 0, 0);
    }
#pragma unroll
    for (int mi = 0; mi < 4; ++mi) {
#pragma unroll
        for (int ni = 0; ni < 4; ++ni) {
#pragma unroll
            for (int j = 0; j < 4; ++j) {
                int row = blockIdx.y * 128 + m0w + mi * 16 + lg * 4 + j;
                int col = blockIdx.x * 128 + n0w + ni * 16 + lq;
                float val = acc[mi][ni][j];
                if (OUT_BF16)
                    ((u16*)C)[(size_t)row * N + col] = f2bf(val);
                else
                    ((float*)C)[(size_t)row * N + col] = val;
            }
        }
    }
}

// ---------------- attention tile compute (one 16q x 64k tile for one wave)
// Constant-shift softmax: p = exp2(s*CLOG - MOFF), MOFF = 8*log2(e). Shift-invariant
// => no max tracking; partials across k-splits sum exactly.
template <bool DIAG>
__device__ __forceinline__ void attn_tile(const u16 (*__restrict__ Kt)[72],
                                          const u16 (*__restrict__ Vt)[72],
                                          const short8v* __restrict__ qf,
                                          f32x4* __restrict__ o,
                                          float& l_r,
                                          int lq, int lg, int wid, int kt64, int qg) {
    const float CLOG = 0.18033688011112042f;   // log2(e)/sqrt(64)
    const float MOFF = 11.541560327111707f;    // 8*log2(e)
    int ksmax = DIAG ? wid : 3;
    f32x4 st[4] = {};
    __builtin_amdgcn_s_setprio(1);
#pragma unroll
    for (int ks = 0; ks < 4; ++ks) {
        if (ks <= ksmax) {
            short8v a0 = *reinterpret_cast<const short8v*>(&Kt[ks * 16 + lq][lg * 8]);
            short8v a1 = *reinterpret_cast<const short8v*>(&Kt[ks * 16 + lq][32 + lg * 8]);
            st[ks] = __builtin_amdgcn_mfma_f32_16x16x32_bf16(a0, qf[0], st[ks], 0, 0, 0);
            st[ks] = __builtin_amdgcn_mfma_f32_16x16x32_bf16(a1, qf[1], st[ks], 0, 0, 0);
        }
    }
    __builtin_amdgcn_s_setprio(0);
    float p[4][4];
    float psum = 0.f;
#pragma unroll
    for (int ks = 0; ks < 4; ++ks)
#pragma unroll
        for (int j = 0; j < 4; ++j) {
            float v = st[ks][j];
            if (DIAG) {
                int kg = kt64 + ks * 16 + lg * 4 + j;
                v = (ks <= ksmax && kg <= qg) ? v : -INFINITY;
            }
            float pv = exp2f(fmaf(v, CLOG, -MOFF));
            p[ks][j] = pv;
            psum += pv;
        }
    l_r += psum;
    u32 w[4][2];
#pragma unroll
    for (int ks = 0; ks < 4; ++ks) {
        w[ks][0] = cvt_pk_bf16(p[ks][0], p[ks][1]);
        w[ks][1] = cvt_pk_bf16(p[ks][2], p[ks][3]);
    }
    int srcA = lq + (((2 * lg) & 3) << 4);
    int srcB = lq + (((2 * lg + 1) & 3) << 4);
    bool hi = (lg & 2);
    short8v pa[2];
#pragma unroll
    for (int f = 0; f < 2; ++f) {
        union { u32 pw[4]; short8v v; } u;
        {
            u32 t0 = (u32)__shfl((int)w[2 * f][0], srcA);
            u32 t1 = (u32)__shfl((int)w[2 * f + 1][0], srcA);
            u.pw[0] = hi ? t1 : t0;
        }
        {
            u32 t0 = (u32)__shfl((int)w[2 * f][1], srcA);
            u32 t1 = (u32)__shfl((int)w[2 * f + 1][1], srcA);
            u.pw[1] = hi ? t1 : t0;
        }
        {
            u32 t0 = (u32)__shfl((int)w[2 * f][0], srcB);
            u32 t1 = (u32)__shfl((int)w[2 * f + 1][0], srcB);
            u.pw[2] = hi ? t1 : t0;
        }
        {
            u32 t0 = (u32)__shfl((int)w[2 * f][1], srcB);
            u32 t1 = (u32)__shfl((int)w[2 * f + 1][1], srcB);
            u.pw[3] = hi ? t1 : t0;
        }
        pa[f] = u.v;
    }
    __builtin_amdgcn_s_setprio(1);
#pragma unroll
    for (int ni = 0; ni < 4; ++ni) {
        int d = ni * 16 + lq;
        int sw = ((d >> 3) & 7) << 3;
        const u16* vrow = Vt[d];
        short8v vb0 = *reinterpret_cast<const short8v*>(&vrow[(lg * 8) ^ sw]);
        short8v vb1 = *reinterpret_cast<const short8v*>(&vrow[(32 + lg * 8) ^ sw]);
        o[ni] = __builtin_amdgcn_mfma_f32_16x16x32_bf16(pa[0], vb0, o[ni], 0, 0, 0);
        o[ni] = __builtin_amdgcn_mfma_f32_16x16x32_bf16(pa[1], vb1, o[ni], 0, 0, 0);
    }
    __builtin_amdgcn_s_setprio(0);
}

// ---------------- flash attention, causal, dual q-tile + KV-parity split.
// grid (8, 64, 2): block handles qblk pair (bx, 15-bx) over k-tiles kt ≡ z (mod 2).
// Constant-shift softmax => partial (o, l) sums combine by pure addition.
__global__ __launch_bounds__(256) void attn_kernel(const u16* __restrict__ qkv,
                                                   float* __restrict__ oP,
                                                   float* __restrict__ lP) {
    int tid = threadIdx.x;
    int lane = tid & 63, wid = tid >> 6;
    int lq = lane & 15, lg = lane >> 4;
    int bh = blockIdx.y;
    int b = bh >> 4, h = bh & 15;
    int h2 = blockIdx.z;
    int qlo_blk = blockIdx.x;
    int qhi_blk = 15 - qlo_blk;
    int qt_lo = qlo_blk * 64 + wid * 16;
    int qt_hi = qhi_blk * 64 + wid * 16;

    const u16* base = qkv + (size_t)b * T_SEQ * THREE_E;
    const u16* Qb = base + h * HD;
    const u16* Kb = base + E_DIM + h * HD;

    __shared__ __align__(16) u16 Kt[2][64][72];
    __shared__ __align__(16) u16 Vt[2][64][72];

    short8v qf_lo[2], qf_hi[2];
    {
        const u16* qr = Qb + (size_t)(qt_lo + lq) * THREE_E + lg * 8;
        qf_lo[0] = *reinterpret_cast<const short8v*>(qr);
        qf_lo[1] = *reinterpret_cast<const short8v*>(qr + 32);
        qr = Qb + (size_t)(qt_hi + lq) * THREE_E + lg * 8;
        qf_hi[0] = *reinterpret_cast<const short8v*>(qr);
        qf_hi[1] = *reinterpret_cast<const short8v*>(qr + 32);
    }
    f32x4 o_lo[4] = {}, o_hi[4] = {};
    float l_lo = 0.f, l_hi = 0.f;
    int qg_lo = qt_lo + lq, qg_hi = qt_hi + lq;

    int row_s = tid >> 3, c8 = tid & 7;
    short8v kreg[2], vreg[2];

    // prologue: stage tile kt=h2 into buf0; prefetch kt=h2+2 into regs
#pragma unroll
    for (int i = 0; i < 2; ++i) {
        const u16* src = Kb + (size_t)(h2 * 64 + row_s + i * 32) * THREE_E + c8 * 8;
        kreg[i] = *reinterpret_cast<const short8v*>(src);
        vreg[i] = *reinterpret_cast<const short8v*>(src + E_DIM);
    }
#pragma unroll
    for (int i = 0; i < 2; ++i) {
        int row = row_s + i * 32;
        *reinterpret_cast<short8v*>(&Kt[0][row][c8 * 8]) = kreg[i];
        int rs = row ^ (c8 << 3);
#pragma unroll
        for (int e = 0; e < 8; ++e) Vt[0][c8 * 8 + e][rs] = (u16)vreg[i][e];
    }
    if (h2 + 2 <= qhi_blk) {
#pragma unroll
        for (int i = 0; i < 2; ++i) {
            const u16* src = Kb + (size_t)((h2 + 2) * 64 + row_s + i * 32) * THREE_E + c8 * 8;
            kreg[i] = *reinterpret_cast<const short8v*>(src);
            vreg[i] = *reinterpret_cast<const short8v*>(src + E_DIM);
        }
    }
    __syncthreads();

    int it = 0;
    for (int kt = h2; kt <= qhi_blk; kt += 2, ++it) {
        int cur = it & 1;
        if (kt + 2 <= qhi_blk) {
#pragma unroll
            for (int i = 0; i < 2; ++i) {
                int row = row_s + i * 32;
                *reinterpret_cast<short8v*>(&Kt[cur ^ 1][row][c8 * 8]) = kreg[i];
                int rs = row ^ (c8 << 3);
#pragma unroll
                for (int e = 0; e < 8; ++e) Vt[cur ^ 1][c8 * 8 + e][rs] = (u16)vreg[i][e];
            }
            if (kt + 4 <= qhi_blk) {
#pragma unroll
                for (int i = 0; i < 2; ++i) {
                    const u16* src = Kb + (size_t)((kt + 4) * 64 + row_s + i * 32) * THREE_E + c8 * 8;
                    kreg[i] = *reinterpret_cast<const short8v*>(src);
                    vreg[i] = *reinterpret_cast<const short8v*>(src + E_DIM);
                }
            }
        }
        if (kt < qlo_blk)
            attn_tile<false>(Kt[cur], Vt[cur], qf_lo, o_lo, l_lo, lq, lg, wid, kt * 64, qg_lo);
        else if (kt == qlo_blk)
            attn_tile<true>(Kt[cur], Vt[cur], qf_lo, o_lo, l_lo, lq, lg, wid, kt * 64, qg_lo);
        if (kt == qhi_blk)
            attn_tile<true>(Kt[cur], Vt[cur], qf_hi, o_hi, l_hi, lq, lg, wid, kt * 64, qg_hi);
        else
            attn_tile<false>(Kt[cur], Vt[cur], qf_hi, o_hi, l_hi, lq, lg, wid, kt * 64, qg_hi);
        __syncthreads();
    }
    // epilogue: write f32 partials (no normalization)
    float lf_lo = l_lo, lf_hi = l_hi;
    lf_lo += __shfl_xor(lf_lo, 16); lf_lo += __shfl_xor(lf_lo, 32);
    lf_hi += __shfl_xor(lf_hi, 16); lf_hi += __shfl_xor(lf_hi, 32);
    if (lane < 16) {
        lP[((size_t)h2 * NTOK + (size_t)b * T_SEQ + qt_lo + lq) * NH + h] = lf_lo;
        lP[((size_t)h2 * NTOK + (size_t)b * T_SEQ + qt_hi + lq) * NH + h] = lf_hi;
    }
    float* oPh = oP + (size_t)h2 * NTOK * E_DIM;
#pragma unroll
    for (int j = 0; j < 4; ++j) {
        size_t row = (size_t)b * T_SEQ + qt_lo + lg * 4 + j;
#pragma unroll
        for (int ni = 0; ni < 4; ++ni)
            oPh[row * E_DIM + h * HD + ni * 16 + lq] = o_lo[ni][j];
    }
#pragma unroll
    for (int j = 0; j < 4; ++j) {
        size_t row = (size_t)b * T_SEQ + qt_hi + lg * 4 + j;
#pragma unroll
        for (int ni = 0; ni < 4; ++ni)
            oPh[row * E_DIM + h * HD + ni * 16 + lq] = o_hi[ni][j];
    }
}

// ---------------- combine: aout = (o0+o1)/(l0+l1), bf16
__global__ __launch_bounds__(256) void attn_combine_kernel(const float* __restrict__ oP,
                                                           const float* __restrict__ lP,
                                                           u16* __restrict__ aout) {
    int idx = blockIdx.x * 256 + threadIdx.x;   // over 4096*1024/4 float4s
    int base = idx * 4;
    int row = base >> 10;
    int h = (base & 1023) >> 6;
    float l = lP[(size_t)row * NH + h] + lP[(size_t)NTOK * NH + (size_t)row * NH + h];
    float4 o0 = reinterpret_cast<const float4*>(oP)[idx];
    float4 o1 = reinterpret_cast<const float4*>(oP + (size_t)NTOK * E_DIM)[idx];
    float inv = 1.0f / l;
    u16* o = aout + base;
    o[0] = f2bf((o0.x + o1.x) * inv);
    o[1] = f2bf((o0.y + o1.y) * inv);
    o[2] = f2bf((o0.z + o1.z) * inv);
    o[3] = f2bf((o0.w + o1.w) * inv);
}

// ---------------- launch
extern "C" void kernel_launch(void* const* d_in, const int* in_sizes, int n_in,
                              void* d_out, int out_size, void* d_ws, size_t ws_size,
                              hipStream_t stream) {
    const float* x = (const float*)d_in[0];
    const float* scale = (const float*)d_in[1];
    const float* w_qkv = (const float*)d_in[2];
    const float* w_proj = (const float*)d_in[3];
    float* out = (float*)d_out;

    char* ws = (char*)d_ws;
    u16* xn    = (u16*)(ws);                    // 8 MB
    u16* wqb   = (u16*)(ws + (8ull << 20));     // 6 MB
    u16* wpb   = (u16*)(ws + (14ull << 20));    // 2 MB
    u16* qkv   = (u16*)(ws + (16ull << 20));    // 24 MB
    u16* aout  = (u16*)(ws + (40ull << 20));    // 8 MB
    float* oP  = (float*)(ws + (48ull << 20));  // 2 x 16 MB f32 partials
    float* lP  = (float*)(ws + (82ull << 20));  // 2 x 256 KB

    rmsnorm_kernel<<<dim3(NTOK), dim3(256), 0, stream>>>(x, scale, xn);
    cast_weights_kernel<<<dim3(4096), dim3(256), 0, stream>>>(w_qkv, w_proj, wqb, wpb);
    gemm8_kernel<E_DIM><<<dim3(THREE_E / 192, NTOK / 256), dim3(512), 0, stream>>>(
        xn, wqb, qkv, THREE_E);
    attn_kernel<<<dim3(8, B_SZ * NH, 2), dim3(256), 0, stream>>>(qkv, oP, lP);
    attn_combine_kernel<<<dim3(NTOK * E_DIM / 1024), dim3(256), 0, stream>>>(oP, lP, aout);
    gemm_lds_kernel<false><<<dim3(E_DIM / 128, NTOK / 128), dim3(256), 0, stream>>>(
        aout, wpb, (void*)out, E_DIM, E_DIM);
}

// Round 7
// 98.488 us; speedup vs baseline: 1.2169x; 1.2169x over previous
//
#include <hip/hip_runtime.h>
#include <hip/hip_bf16.h>
#include <stdint.h>

#define B_SZ 4
#define T_SEQ 1024
#define E_DIM 1024
#define NH 16
#define HD 64
#define THREE_E 3072
#define NTOK 4096

typedef unsigned short u16;
typedef unsigned int u32;
using short8v = __attribute__((ext_vector_type(8))) short;
using short4v = __attribute__((ext_vector_type(4))) short;
using f32x4 = __attribute__((ext_vector_type(4))) float;

__device__ __forceinline__ u16 f2bf(float f) {
    union { float f; uint32_t u; } c; c.f = f;
    uint32_t u = c.u;
    uint32_t r = (u + 0x7FFFu + ((u >> 16) & 1u)) >> 16;
    return (u16)r;
}

__device__ __forceinline__ u32 cvt_pk_bf16(float lo, float hi) {
    u32 r;
    asm("v_cvt_pk_bf16_f32 %0, %1, %2" : "=v"(r) : "v"(lo), "v"(hi));
    return r;
}

__device__ __forceinline__ void gload_lds16(const u16* g, u16* l) {
    __builtin_amdgcn_global_load_lds((const __attribute__((address_space(1))) void*)g,
                                     (__attribute__((address_space(3))) void*)l, 16, 0, 0);
}

// ---------------- RMSNorm: x[4096][1024] f32 -> bf16
__global__ __launch_bounds__(256) void rmsnorm_kernel(const float* __restrict__ x,
                                                      const float* __restrict__ scale,
                                                      u16* __restrict__ xn) {
    int row = blockIdx.x;
    int tid = threadIdx.x;
    const float4* xr = reinterpret_cast<const float4*>(x + (size_t)row * E_DIM);
    float4 v = xr[tid];
    float ss = v.x * v.x + v.y * v.y + v.z * v.z + v.w * v.w;
    for (int off = 32; off > 0; off >>= 1) ss += __shfl_xor(ss, off);
    __shared__ float red[4];
    if ((tid & 63) == 0) red[tid >> 6] = ss;
    __syncthreads();
    float total = red[0] + red[1] + red[2] + red[3];
    float rs = rsqrtf(total * (1.0f / E_DIM) + 1e-5f);
    const float4* sc4 = reinterpret_cast<const float4*>(scale);
    float4 s = sc4[tid];
    u16* o = xn + (size_t)row * E_DIM + tid * 4;
    o[0] = f2bf(v.x * rs * s.x);
    o[1] = f2bf(v.y * rs * s.y);
    o[2] = f2bf(v.z * rs * s.z);
    o[3] = f2bf(v.w * rs * s.w);
}

// ---------------- weight f32 -> bf16 cast
__global__ __launch_bounds__(256) void cast_weights_kernel(const float* __restrict__ wq,
                                                           const float* __restrict__ wp,
                                                           u16* __restrict__ wqb,
                                                           u16* __restrict__ wpb) {
    const int NQ = (THREE_E * E_DIM) / 4;
    const int NP = (E_DIM * E_DIM) / 4;
    int i = blockIdx.x * 256 + threadIdx.x;
    if (i < NQ) {
        float4 v = reinterpret_cast<const float4*>(wq)[i];
        u16* o = wqb + (size_t)i * 4;
        o[0] = f2bf(v.x); o[1] = f2bf(v.y); o[2] = f2bf(v.z); o[3] = f2bf(v.w);
    } else if (i < NQ + NP) {
        int j = i - NQ;
        float4 v = reinterpret_cast<const float4*>(wp)[j];
        u16* o = wpb + (size_t)j * 4;
        o[0] = f2bf(v.x); o[1] = f2bf(v.y); o[2] = f2bf(v.z); o[3] = f2bf(v.w);
    }
}

// ---------------- 2-phase GEMM, 128x128 tile, BK=64 (32 MFMA per barrier-pair),
// chunk-XOR LDS swizzle both sides (T2 + rule #21), bijective XCD swizzle (T1).
// C[m][n] = sum_k A[m][k] * Bw[n][k]  (both bf16, k-contiguous)
template <bool OUT_BF16>
__global__ __launch_bounds__(256) void gemm_lds_kernel(const u16* __restrict__ A,
                                                       const u16* __restrict__ Bw,
                                                       void* __restrict__ C,
                                                       int N, int K) {
    __shared__ u16 As[128 * 64];   // 16 KB, [row][col] with col-chunk c stored at c^(row&7)
    __shared__ u16 Bs[128 * 64];
    int tid = threadIdx.x;
    int lane = tid & 63, wid = tid >> 6;
    int lq = lane & 15, lg = lane >> 4;

    // XCD-aware bijective block swizzle (grid size % 8 == 0 for both uses)
    int gx = gridDim.x;
    int nwg = gx * gridDim.y;
    int orig = blockIdx.y * gx + blockIdx.x;
    int cpx = nwg >> 3;
    int swz = (orig & 7) * cpx + (orig >> 3);
    int bx = swz % gx, by = swz / gx;
    int mblk = by * 128, nblk = bx * 128;

    // staging: wave wid covers rows [wid*32, +32); inst i covers 8 rows.
    int srow = wid * 32 + (lane >> 3);
    int csw = ((lane & 7) ^ ((lane >> 3) & 7)) * 8;   // pre-swizzled source chunk
    const u16* gA = A + (size_t)(mblk + srow) * K + csw;
    const u16* gB = Bw + (size_t)(nblk + srow) * K + csw;
    u16* lA = As + wid * 2048;
    u16* lB = Bs + wid * 2048;

    f32x4 acc[4][4] = {};
    int m0w = (wid >> 1) * 64;
    int n0w = (wid & 1) * 64;
    int r7 = lq & 7;

    for (int k0 = 0; k0 < K; k0 += 64) {
        __syncthreads();
#pragma unroll
        for (int i = 0; i < 4; ++i) gload_lds16(gA + k0 + (size_t)i * 8 * K, lA + i * 512);
#pragma unroll
        for (int i = 0; i < 4; ++i) gload_lds16(gB + k0 + (size_t)i * 8 * K, lB + i * 512);
        __syncthreads();
        short8v af[2][4], bf[2][4];
#pragma unroll
        for (int kk = 0; kk < 2; ++kk) {
#pragma unroll
            for (int mi = 0; mi < 4; ++mi)
                af[kk][mi] = *reinterpret_cast<const short8v*>(
                    &As[(m0w + mi * 16 + lq) * 64 + ((kk * 4 + lg) ^ r7) * 8]);
#pragma unroll
            for (int ni = 0; ni < 4; ++ni)
                bf[kk][ni] = *reinterpret_cast<const short8v*>(
                    &Bs[(n0w + ni * 16 + lq) * 64 + ((kk * 4 + lg) ^ r7) * 8]);
        }
        __builtin_amdgcn_s_setprio(1);
#pragma unroll
        for (int mi = 0; mi < 4; ++mi)
#pragma unroll
            for (int ni = 0; ni < 4; ++ni) {
                acc[mi][ni] = __builtin_amdgcn_mfma_f32_16x16x32_bf16(af[0][mi], bf[0][ni], acc[mi][ni], 0, 0, 0);
                acc[mi][ni] = __builtin_amdgcn_mfma_f32_16x16x32_bf16(af[1][mi], bf[1][ni], acc[mi][ni], 0, 0, 0);
            }
        __builtin_amdgcn_s_setprio(0);
    }
#pragma unroll
    for (int mi = 0; mi < 4; ++mi) {
#pragma unroll
        for (int ni = 0; ni < 4; ++ni) {
#pragma unroll
            for (int j = 0; j < 4; ++j) {
                int row = mblk + m0w + mi * 16 + lg * 4 + j;
                int col = nblk + n0w + ni * 16 + lq;
                float val = acc[mi][ni][j];
                if (OUT_BF16)
                    ((u16*)C)[(size_t)row * N + col] = f2bf(val);
                else
                    ((float*)C)[(size_t)row * N + col] = val;
            }
        }
    }
}

// ---------------- attention tile compute (one 16q x 64k tile for one wave)
// Constant-shift softmax (shift-invariant, scores bounded): no max tracking.
// PV via 16x16x16 MFMA: A-frag = own cvt_pk'd P words (C-layout == A-layout for K=16),
// zero cross-lane exchange.
template <bool DIAG>
__device__ __forceinline__ void attn_tile(const u16 (*__restrict__ Kt)[72],
                                          const u16 (*__restrict__ Vt)[72],
                                          const short8v* __restrict__ qf,
                                          f32x4* __restrict__ o,
                                          float& l_r,
                                          int lq, int lg, int wid, int kt64, int qg) {
    const float CLOG = 0.18033688011112042f;   // log2(e)/sqrt(64)
    const float MOFF = 11.541560327111707f;    // 8*log2(e)
    int ksmax = DIAG ? wid : 3;
    f32x4 st[4] = {};
    __builtin_amdgcn_s_setprio(1);
#pragma unroll
    for (int ks = 0; ks < 4; ++ks) {
        if (ks <= ksmax) {
            short8v a0 = *reinterpret_cast<const short8v*>(&Kt[ks * 16 + lq][lg * 8]);
            short8v a1 = *reinterpret_cast<const short8v*>(&Kt[ks * 16 + lq][32 + lg * 8]);
            st[ks] = __builtin_amdgcn_mfma_f32_16x16x32_bf16(a0, qf[0], st[ks], 0, 0, 0);
            st[ks] = __builtin_amdgcn_mfma_f32_16x16x32_bf16(a1, qf[1], st[ks], 0, 0, 0);
        }
    }
    __builtin_amdgcn_s_setprio(0);
    // p = exp2(s*CLOG - MOFF); masked -> 0
    float p[4][4];
    float psum = 0.f;
#pragma unroll
    for (int ks = 0; ks < 4; ++ks)
#pragma unroll
        for (int j = 0; j < 4; ++j) {
            float v = st[ks][j];
            if (DIAG) {
                int kg = kt64 + ks * 16 + lg * 4 + j;
                v = (ks <= ksmax && kg <= qg) ? v : -INFINITY;
            }
            float pv = exp2f(fmaf(v, CLOG, -MOFF));
            p[ks][j] = pv;
            psum += pv;
        }
    l_r += psum;
    // pack P rows into bf16 A-frags for 16x16x16 PV (own data, no exchange)
    union { u32 w2[2]; short4v v; } pa[4];
#pragma unroll
    for (int ks = 0; ks < 4; ++ks) {
        pa[ks].w2[0] = cvt_pk_bf16(p[ks][0], p[ks][1]);
        pa[ks].w2[1] = cvt_pk_bf16(p[ks][2], p[ks][3]);
    }
    // PV: O[q=lq][d] += P[q][k] V[k][d], 4 k-slices of 16
    __builtin_amdgcn_s_setprio(1);
#pragma unroll
    for (int ni = 0; ni < 4; ++ni) {
        int d = ni * 16 + lq;
        int sw = ((d >> 3) & 7) << 3;
        const u16* vrow = Vt[d];
#pragma unroll
        for (int ks = 0; ks < 4; ++ks) {
            if (ks <= ksmax) {
                short4v vb = *reinterpret_cast<const short4v*>(&vrow[(ks * 16 + lg * 4) ^ sw]);
                o[ni] = __builtin_amdgcn_mfma_f32_16x16x16bf16_1k(pa[ks].v, vb, o[ni], 0, 0, 0);
            }
        }
    }
    __builtin_amdgcn_s_setprio(0);
}

// ---------------- flash attention, causal, balanced dual q-tile blocks.
// grid: (8, 64). Block handles qblk_lo = bx AND qblk_hi = 15-bx (uniform 17 units).
// Double-buffered K/V LDS: ONE barrier per k-tile.
__global__ __launch_bounds__(256) void attn_kernel(const u16* __restrict__ qkv,
                                                   u16* __restrict__ out) {
    int tid = threadIdx.x;
    int lane = tid & 63, wid = tid >> 6;
    int lq = lane & 15, lg = lane >> 4;
    int bh = blockIdx.y;
    int b = bh >> 4, h = bh & 15;
    int qlo_blk = blockIdx.x;
    int qhi_blk = 15 - qlo_blk;
    int qt_lo = qlo_blk * 64 + wid * 16;
    int qt_hi = qhi_blk * 64 + wid * 16;

    const u16* base = qkv + (size_t)b * T_SEQ * THREE_E;
    const u16* Qb = base + h * HD;
    const u16* Kb = base + E_DIM + h * HD;

    __shared__ __align__(16) u16 Kt[2][64][72];
    __shared__ __align__(16) u16 Vt[2][64][72];

    short8v qf_lo[2], qf_hi[2];
    {
        const u16* qr = Qb + (size_t)(qt_lo + lq) * THREE_E + lg * 8;
        qf_lo[0] = *reinterpret_cast<const short8v*>(qr);
        qf_lo[1] = *reinterpret_cast<const short8v*>(qr + 32);
        qr = Qb + (size_t)(qt_hi + lq) * THREE_E + lg * 8;
        qf_hi[0] = *reinterpret_cast<const short8v*>(qr);
        qf_hi[1] = *reinterpret_cast<const short8v*>(qr + 32);
    }
    f32x4 o_lo[4] = {}, o_hi[4] = {};
    float l_lo = 0.f, l_hi = 0.f;
    int qg_lo = qt_lo + lq, qg_hi = qt_hi + lq;

    int row_s = tid >> 3, c8 = tid & 7;
    short8v kreg[2], vreg[2];

    // prologue: stage tile 0 into buf0, prefetch tile 1
#pragma unroll
    for (int i = 0; i < 2; ++i) {
        const u16* src = Kb + (size_t)(row_s + i * 32) * THREE_E + c8 * 8;
        kreg[i] = *reinterpret_cast<const short8v*>(src);
        vreg[i] = *reinterpret_cast<const short8v*>(src + E_DIM);
    }
#pragma unroll
    for (int i = 0; i < 2; ++i) {
        int row = row_s + i * 32;
        *reinterpret_cast<short8v*>(&Kt[0][row][c8 * 8]) = kreg[i];
        int rs = row ^ (c8 << 3);
#pragma unroll
        for (int e = 0; e < 8; ++e) Vt[0][c8 * 8 + e][rs] = (u16)vreg[i][e];
    }
    if (qhi_blk >= 1) {
#pragma unroll
        for (int i = 0; i < 2; ++i) {
            const u16* src = Kb + (size_t)(64 + row_s + i * 32) * THREE_E + c8 * 8;
            kreg[i] = *reinterpret_cast<const short8v*>(src);
            vreg[i] = *reinterpret_cast<const short8v*>(src + E_DIM);
        }
    }
    __syncthreads();

    for (int kt = 0; kt <= qhi_blk; ++kt) {
        int cur = kt & 1;
        if (kt < qhi_blk) {
#pragma unroll
            for (int i = 0; i < 2; ++i) {
                int row = row_s + i * 32;
                *reinterpret_cast<short8v*>(&Kt[cur ^ 1][row][c8 * 8]) = kreg[i];
                int rs = row ^ (c8 << 3);
#pragma unroll
                for (int e = 0; e < 8; ++e) Vt[cur ^ 1][c8 * 8 + e][rs] = (u16)vreg[i][e];
            }
            if (kt + 1 < qhi_blk) {
#pragma unroll
                for (int i = 0; i < 2; ++i) {
                    const u16* src = Kb + (size_t)((kt + 2) * 64 + row_s + i * 32) * THREE_E + c8 * 8;
                    kreg[i] = *reinterpret_cast<const short8v*>(src);
                    vreg[i] = *reinterpret_cast<const short8v*>(src + E_DIM);
                }
            }
        }
        if (kt < qlo_blk)
            attn_tile<false>(Kt[cur], Vt[cur], qf_lo, o_lo, l_lo, lq, lg, wid, kt * 64, qg_lo);
        else if (kt == qlo_blk)
            attn_tile<true>(Kt[cur], Vt[cur], qf_lo, o_lo, l_lo, lq, lg, wid, kt * 64, qg_lo);
        if (kt < qhi_blk)
            attn_tile<false>(Kt[cur], Vt[cur], qf_hi, o_hi, l_hi, lq, lg, wid, kt * 64, qg_hi);
        else
            attn_tile<true>(Kt[cur], Vt[cur], qf_hi, o_hi, l_hi, lq, lg, wid, kt * 64, qg_hi);
        __syncthreads();
    }
    // epilogue: reduce l across the 4 lanes sharing lq, normalize, store bf16
    float lf_lo = l_lo, lf_hi = l_hi;
    lf_lo += __shfl_xor(lf_lo, 16); lf_lo += __shfl_xor(lf_lo, 32);
    lf_hi += __shfl_xor(lf_hi, 16); lf_hi += __shfl_xor(lf_hi, 32);
#pragma unroll
    for (int j = 0; j < 4; ++j) {
        float linv = 1.0f / __shfl(lf_lo, lg * 4 + j);
        size_t row = (size_t)b * T_SEQ + qt_lo + lg * 4 + j;
#pragma unroll
        for (int ni = 0; ni < 4; ++ni)
            out[row * E_DIM + h * HD + ni * 16 + lq] = f2bf(o_lo[ni][j] * linv);
    }
#pragma unroll
    for (int j = 0; j < 4; ++j) {
        float linv = 1.0f / __shfl(lf_hi, lg * 4 + j);
        size_t row = (size_t)b * T_SEQ + qt_hi + lg * 4 + j;
#pragma unroll
        for (int ni = 0; ni < 4; ++ni)
            out[row * E_DIM + h * HD + ni * 16 + lq] = f2bf(o_hi[ni][j] * linv);
    }
}

// ---------------- launch
extern "C" void kernel_launch(void* const* d_in, const int* in_sizes, int n_in,
                              void* d_out, int out_size, void* d_ws, size_t ws_size,
                              hipStream_t stream) {
    const float* x = (const float*)d_in[0];
    const float* scale = (const float*)d_in[1];
    const float* w_qkv = (const float*)d_in[2];
    const float* w_proj = (const float*)d_in[3];
    float* out = (float*)d_out;

    char* ws = (char*)d_ws;
    u16* xn   = (u16*)(ws);                    // 8 MB
    u16* wqb  = (u16*)(ws + (8ull << 20));     // 6 MB
    u16* wpb  = (u16*)(ws + (14ull << 20));    // 2 MB
    u16* qkv  = (u16*)(ws + (16ull << 20));    // 24 MB
    u16* aout = (u16*)(ws + (40ull << 20));    // 8 MB

    rmsnorm_kernel<<<dim3(NTOK), dim3(256), 0, stream>>>(x, scale, xn);
    cast_weights_kernel<<<dim3(4096), dim3(256), 0, stream>>>(w_qkv, w_proj, wqb, wpb);
    gemm_lds_kernel<true><<<dim3(THREE_E / 128, NTOK / 128), dim3(256), 0, stream>>>(
        xn, wqb, (void*)qkv, THREE_E, E_DIM);
    attn_kernel<<<dim3(8, B_SZ * NH), dim3(256), 0, stream>>>(qkv, aout);
    gemm_lds_kernel<false><<<dim3(E_DIM / 128, NTOK / 128), dim3(256), 0, stream>>>(
        aout, wpb, (void*)out, E_DIM, E_DIM);
}

// Round 8
// 89.668 us; speedup vs baseline: 1.3366x; 1.0984x over previous
//
#include <hip/hip_runtime.h>
#include <hip/hip_bf16.h>
#include <stdint.h>

#define B_SZ 4
#define T_SEQ 1024
#define E_DIM 1024
#define NH 16
#define HD 64
#define THREE_E 3072
#define NTOK 4096

typedef unsigned short u16;
typedef unsigned int u32;
using short8v = __attribute__((ext_vector_type(8))) short;
using short4v = __attribute__((ext_vector_type(4))) short;
using f32x4 = __attribute__((ext_vector_type(4))) float;

__device__ __forceinline__ u16 f2bf(float f) {
    union { float f; uint32_t u; } c; c.f = f;
    uint32_t u = c.u;
    uint32_t r = (u + 0x7FFFu + ((u >> 16) & 1u)) >> 16;
    return (u16)r;
}

__device__ __forceinline__ u32 cvt_pk_bf16(float lo, float hi) {
    u32 r;
    asm("v_cvt_pk_bf16_f32 %0, %1, %2" : "=v"(r) : "v"(lo), "v"(hi));
    return r;
}

__device__ __forceinline__ void gload_lds16(const u16* g, u16* l) {
    __builtin_amdgcn_global_load_lds((const __attribute__((address_space(1))) void*)g,
                                     (__attribute__((address_space(3))) void*)l, 16, 0, 0);
}

// ---------------- fused prep: RMSNorm (blocks 0..4095) + weight cast (4096..8191)
__global__ __launch_bounds__(256) void prep_kernel(const float* __restrict__ x,
                                                   const float* __restrict__ scale,
                                                   const float* __restrict__ wq,
                                                   const float* __restrict__ wp,
                                                   u16* __restrict__ xn,
                                                   u16* __restrict__ wqb,
                                                   u16* __restrict__ wpb) {
    int bx = blockIdx.x;
    int tid = threadIdx.x;
    if (bx < 4096) {
        int row = bx;
        const float4* xr = reinterpret_cast<const float4*>(x + (size_t)row * E_DIM);
        float4 v = xr[tid];
        float ss = v.x * v.x + v.y * v.y + v.z * v.z + v.w * v.w;
        for (int off = 32; off > 0; off >>= 1) ss += __shfl_xor(ss, off);
        __shared__ float red[4];
        if ((tid & 63) == 0) red[tid >> 6] = ss;
        __syncthreads();
        float total = red[0] + red[1] + red[2] + red[3];
        float rs = rsqrtf(total * (1.0f / E_DIM) + 1e-5f);
        float4 s = reinterpret_cast<const float4*>(scale)[tid];
        u16* o = xn + (size_t)row * E_DIM + tid * 4;
        o[0] = f2bf(v.x * rs * s.x);
        o[1] = f2bf(v.y * rs * s.y);
        o[2] = f2bf(v.z * rs * s.z);
        o[3] = f2bf(v.w * rs * s.w);
    } else {
        const int NQ = (THREE_E * E_DIM) / 4;
        const int NP = (E_DIM * E_DIM) / 4;
        int i = (bx - 4096) * 256 + tid;
        if (i < NQ) {
            float4 v = reinterpret_cast<const float4*>(wq)[i];
            u16* o = wqb + (size_t)i * 4;
            o[0] = f2bf(v.x); o[1] = f2bf(v.y); o[2] = f2bf(v.z); o[3] = f2bf(v.w);
        } else if (i < NQ + NP) {
            int j = i - NQ;
            float4 v = reinterpret_cast<const float4*>(wp)[j];
            u16* o = wpb + (size_t)j * 4;
            o[0] = f2bf(v.x); o[1] = f2bf(v.y); o[2] = f2bf(v.z); o[3] = f2bf(v.w);
        }
    }
}

// ---------------- 2-phase GEMM, 128xBN tile, BK=64, chunk-XOR LDS swizzle both sides,
// bijective XCD swizzle. C[m][n] = sum_k A[m][k] * Bw[n][k] (bf16 k-contiguous).
template <int BN, bool OUT_BF16>
__global__ __launch_bounds__(256) void gemm_lds_kernel(const u16* __restrict__ A,
                                                       const u16* __restrict__ Bw,
                                                       void* __restrict__ C,
                                                       int N, int K) {
    constexpr int NFR = BN / 32;          // n-frags per wave
    __shared__ u16 As[128 * 64];
    __shared__ u16 Bs[BN * 64];
    int tid = threadIdx.x;
    int lane = tid & 63, wid = tid >> 6;
    int lq = lane & 15, lg = lane >> 4;

    // XCD-aware bijective block swizzle (nwg % 8 == 0 for all uses)
    int gx = gridDim.x;
    int nwg = gx * gridDim.y;
    int orig = blockIdx.y * gx + blockIdx.x;
    int cpx = nwg >> 3;
    int swz = (orig & 7) * cpx + (orig >> 3);
    int bx = swz % gx, by = swz / gx;
    int mblk = by * 128, nblk = bx * BN;

    int srowA = wid * 32 + (lane >> 3);
    int srowB = wid * (BN / 4) + (lane >> 3);
    int csw = ((lane & 7) ^ ((lane >> 3) & 7)) * 8;   // pre-swizzled source chunk
    const u16* gA = A + (size_t)(mblk + srowA) * K + csw;
    const u16* gB = Bw + (size_t)(nblk + srowB) * K + csw;
    u16* lA = As + wid * 2048;
    u16* lB = Bs + wid * (BN / 4) * 64;

    f32x4 acc[4][NFR] = {};
    int m0w = (wid >> 1) * 64;
    int n0w = (wid & 1) * (BN / 2);
    int r7 = lq & 7;

    for (int k0 = 0; k0 < K; k0 += 64) {
        __syncthreads();
#pragma unroll
        for (int i = 0; i < 4; ++i) gload_lds16(gA + k0 + (size_t)i * 8 * K, lA + i * 512);
#pragma unroll
        for (int i = 0; i < NFR; ++i) gload_lds16(gB + k0 + (size_t)i * 8 * K, lB + i * 512);
        __syncthreads();
        short8v af[2][4], bf[2][NFR];
#pragma unroll
        for (int kk = 0; kk < 2; ++kk) {
#pragma unroll
            for (int mi = 0; mi < 4; ++mi)
                af[kk][mi] = *reinterpret_cast<const short8v*>(
                    &As[(m0w + mi * 16 + lq) * 64 + ((kk * 4 + lg) ^ r7) * 8]);
#pragma unroll
            for (int ni = 0; ni < NFR; ++ni)
                bf[kk][ni] = *reinterpret_cast<const short8v*>(
                    &Bs[(n0w + ni * 16 + lq) * 64 + ((kk * 4 + lg) ^ r7) * 8]);
        }
        __builtin_amdgcn_s_setprio(1);
#pragma unroll
        for (int mi = 0; mi < 4; ++mi)
#pragma unroll
            for (int ni = 0; ni < NFR; ++ni) {
                acc[mi][ni] = __builtin_amdgcn_mfma_f32_16x16x32_bf16(af[0][mi], bf[0][ni], acc[mi][ni], 0, 0, 0);
                acc[mi][ni] = __builtin_amdgcn_mfma_f32_16x16x32_bf16(af[1][mi], bf[1][ni], acc[mi][ni], 0, 0, 0);
            }
        __builtin_amdgcn_s_setprio(0);
    }
#pragma unroll
    for (int mi = 0; mi < 4; ++mi) {
#pragma unroll
        for (int ni = 0; ni < NFR; ++ni) {
#pragma unroll
            for (int j = 0; j < 4; ++j) {
                int row = mblk + m0w + mi * 16 + lg * 4 + j;
                int col = nblk + n0w + ni * 16 + lq;
                float val = acc[mi][ni][j];
                if (OUT_BF16)
                    ((u16*)C)[(size_t)row * N + col] = f2bf(val);
                else
                    ((float*)C)[(size_t)row * N + col] = val;
            }
        }
    }
}

// ---------------- attention tile compute (one 16q x 64k tile for one wave)
// Constant-shift softmax (shift-invariant, scores bounded): no max tracking.
// PV via 16x16x16 MFMA: A-frag = own cvt_pk'd P words, zero cross-lane exchange.
template <bool DIAG>
__device__ __forceinline__ void attn_tile(const u16 (*__restrict__ Kt)[72],
                                          const u16 (*__restrict__ Vt)[72],
                                          const short8v* __restrict__ qf,
                                          f32x4* __restrict__ o,
                                          float& l_r,
                                          int lq, int lg, int w4, int kt64, int qg) {
    const float CLOG = 0.18033688011112042f;   // log2(e)/sqrt(64)
    const float MOFF = 11.541560327111707f;    // 8*log2(e)
    int ksmax = DIAG ? w4 : 3;
    f32x4 st[4] = {};
    __builtin_amdgcn_s_setprio(1);
#pragma unroll
    for (int ks = 0; ks < 4; ++ks) {
        if (ks <= ksmax) {
            short8v a0 = *reinterpret_cast<const short8v*>(&Kt[ks * 16 + lq][lg * 8]);
            short8v a1 = *reinterpret_cast<const short8v*>(&Kt[ks * 16 + lq][32 + lg * 8]);
            st[ks] = __builtin_amdgcn_mfma_f32_16x16x32_bf16(a0, qf[0], st[ks], 0, 0, 0);
            st[ks] = __builtin_amdgcn_mfma_f32_16x16x32_bf16(a1, qf[1], st[ks], 0, 0, 0);
        }
    }
    __builtin_amdgcn_s_setprio(0);
    float p[4][4];
    float psum = 0.f;
#pragma unroll
    for (int ks = 0; ks < 4; ++ks)
#pragma unroll
        for (int j = 0; j < 4; ++j) {
            float v = st[ks][j];
            if (DIAG) {
                int kg = kt64 + ks * 16 + lg * 4 + j;
                v = (ks <= ksmax && kg <= qg) ? v : -INFINITY;
            }
            float pv = exp2f(fmaf(v, CLOG, -MOFF));
            p[ks][j] = pv;
            psum += pv;
        }
    l_r += psum;
    union { u32 w2[2]; short4v v; } pa[4];
#pragma unroll
    for (int ks = 0; ks < 4; ++ks) {
        pa[ks].w2[0] = cvt_pk_bf16(p[ks][0], p[ks][1]);
        pa[ks].w2[1] = cvt_pk_bf16(p[ks][2], p[ks][3]);
    }
    __builtin_amdgcn_s_setprio(1);
#pragma unroll
    for (int ni = 0; ni < 4; ++ni) {
        int d = ni * 16 + lq;
        int sw = ((d >> 3) & 7) << 3;
        const u16* vrow = Vt[d];
#pragma unroll
        for (int ks = 0; ks < 4; ++ks) {
            if (ks <= ksmax) {
                short4v vb = *reinterpret_cast<const short4v*>(&vrow[(ks * 16 + lg * 4) ^ sw]);
                o[ni] = __builtin_amdgcn_mfma_f32_16x16x16bf16_1k(pa[ks].v, vb, o[ni], 0, 0, 0);
            }
        }
    }
    __builtin_amdgcn_s_setprio(0);
}

// ---------------- flash attention, causal, balanced dual q-tile blocks, 8 waves.
// grid (8, 64), 512 threads. Waves 0-3: lo qblk tiles; waves 4-7: hi qblk tiles.
// 2 blocks/CU x 8 waves = 16 waves/CU (2x the 4-wave version's latency hiding).
__global__ __launch_bounds__(512) void attn_kernel(const u16* __restrict__ qkv,
                                                   u16* __restrict__ out) {
    int tid = threadIdx.x;
    int lane = tid & 63, wid = tid >> 6;
    int lq = lane & 15, lg = lane >> 4;
    int w4 = wid & 3;
    bool is_hi = wid >= 4;
    int bh = blockIdx.y;
    int b = bh >> 4, h = bh & 15;
    int qlo_blk = blockIdx.x;
    int qhi_blk = 15 - qlo_blk;
    int myblk = is_hi ? qhi_blk : qlo_blk;
    int qt = myblk * 64 + w4 * 16;

    const u16* base = qkv + (size_t)b * T_SEQ * THREE_E;
    const u16* Qb = base + h * HD;
    const u16* Kb = base + E_DIM + h * HD;

    __shared__ __align__(16) u16 Kt[2][64][72];
    __shared__ __align__(16) u16 Vt[2][64][72];

    short8v qf[2];
    {
        const u16* qr = Qb + (size_t)(qt + lq) * THREE_E + lg * 8;
        qf[0] = *reinterpret_cast<const short8v*>(qr);
        qf[1] = *reinterpret_cast<const short8v*>(qr + 32);
    }
    f32x4 o[4] = {};
    float l_r = 0.f;
    int qg = qt + lq;

    int row_s = tid >> 3, c8 = tid & 7;   // 512 threads -> rows 0..63, one 16B each
    short8v kreg, vreg;

    // prologue: stage tile 0 into buf0, prefetch tile 1
    {
        const u16* src = Kb + (size_t)row_s * THREE_E + c8 * 8;
        kreg = *reinterpret_cast<const short8v*>(src);
        vreg = *reinterpret_cast<const short8v*>(src + E_DIM);
    }
    {
        *reinterpret_cast<short8v*>(&Kt[0][row_s][c8 * 8]) = kreg;
        int rs = row_s ^ (c8 << 3);
#pragma unroll
        for (int e = 0; e < 8; ++e) Vt[0][c8 * 8 + e][rs] = (u16)vreg[e];
    }
    if (qhi_blk >= 1) {
        const u16* src = Kb + (size_t)(64 + row_s) * THREE_E + c8 * 8;
        kreg = *reinterpret_cast<const short8v*>(src);
        vreg = *reinterpret_cast<const short8v*>(src + E_DIM);
    }
    __syncthreads();

    for (int kt = 0; kt <= qhi_blk; ++kt) {
        int cur = kt & 1;
        if (kt < qhi_blk) {
            *reinterpret_cast<short8v*>(&Kt[cur ^ 1][row_s][c8 * 8]) = kreg;
            int rs = row_s ^ (c8 << 3);
#pragma unroll
            for (int e = 0; e < 8; ++e) Vt[cur ^ 1][c8 * 8 + e][rs] = (u16)vreg[e];
            if (kt + 1 < qhi_blk) {
                const u16* src = Kb + (size_t)((kt + 2) * 64 + row_s) * THREE_E + c8 * 8;
                kreg = *reinterpret_cast<const short8v*>(src);
                vreg = *reinterpret_cast<const short8v*>(src + E_DIM);
            }
        }
        if (is_hi) {
            if (kt < qhi_blk)
                attn_tile<false>(Kt[cur], Vt[cur], qf, o, l_r, lq, lg, w4, kt * 64, qg);
            else
                attn_tile<true>(Kt[cur], Vt[cur], qf, o, l_r, lq, lg, w4, kt * 64, qg);
        } else {
            if (kt < qlo_blk)
                attn_tile<false>(Kt[cur], Vt[cur], qf, o, l_r, lq, lg, w4, kt * 64, qg);
            else if (kt == qlo_blk)
                attn_tile<true>(Kt[cur], Vt[cur], qf, o, l_r, lq, lg, w4, kt * 64, qg);
        }
        __syncthreads();
    }
    // epilogue: reduce l across the 4 lanes sharing lq, normalize, store bf16
    float lf = l_r;
    lf += __shfl_xor(lf, 16); lf += __shfl_xor(lf, 32);
#pragma unroll
    for (int j = 0; j < 4; ++j) {
        float linv = 1.0f / __shfl(lf, lg * 4 + j);
        size_t row = (size_t)b * T_SEQ + qt + lg * 4 + j;
#pragma unroll
        for (int ni = 0; ni < 4; ++ni)
            out[row * E_DIM + h * HD + ni * 16 + lq] = f2bf(o[ni][j] * linv);
    }
}

// ---------------- launch
extern "C" void kernel_launch(void* const* d_in, const int* in_sizes, int n_in,
                              void* d_out, int out_size, void* d_ws, size_t ws_size,
                              hipStream_t stream) {
    const float* x = (const float*)d_in[0];
    const float* scale = (const float*)d_in[1];
    const float* w_qkv = (const float*)d_in[2];
    const float* w_proj = (const float*)d_in[3];
    float* out = (float*)d_out;

    char* ws = (char*)d_ws;
    u16* xn   = (u16*)(ws);                    // 8 MB
    u16* wqb  = (u16*)(ws + (8ull << 20));     // 6 MB
    u16* wpb  = (u16*)(ws + (14ull << 20));    // 2 MB
    u16* qkv  = (u16*)(ws + (16ull << 20));    // 24 MB
    u16* aout = (u16*)(ws + (40ull << 20));    // 8 MB

    prep_kernel<<<dim3(8192), dim3(256), 0, stream>>>(x, scale, w_qkv, w_proj, xn, wqb, wpb);
    gemm_lds_kernel<128, true><<<dim3(THREE_E / 128, NTOK / 128), dim3(256), 0, stream>>>(
        xn, wqb, (void*)qkv, THREE_E, E_DIM);
    attn_kernel<<<dim3(8, B_SZ * NH), dim3(512), 0, stream>>>(qkv, aout);
    gemm_lds_kernel<64, false><<<dim3(E_DIM / 64, NTOK / 128), dim3(256), 0, stream>>>(
        aout, wpb, (void*)out, E_DIM, E_DIM);
}

// Round 9
// 86.699 us; speedup vs baseline: 1.3824x; 1.0342x over previous
//
#include <hip/hip_runtime.h>
#include <hip/hip_bf16.h>
#include <stdint.h>

#define B_SZ 4
#define T_SEQ 1024
#define E_DIM 1024
#define NH 16
#define HD 64
#define THREE_E 3072
#define NTOK 4096

typedef unsigned short u16;
typedef unsigned int u32;
using short8v = __attribute__((ext_vector_type(8))) short;
using short4v = __attribute__((ext_vector_type(4))) short;
using f32x4 = __attribute__((ext_vector_type(4))) float;

__device__ __forceinline__ u16 f2bf(float f) {
    union { float f; uint32_t u; } c; c.f = f;
    uint32_t u = c.u;
    uint32_t r = (u + 0x7FFFu + ((u >> 16) & 1u)) >> 16;
    return (u16)r;
}

__device__ __forceinline__ u32 cvt_pk_bf16(float lo, float hi) {
    u32 r;
    asm("v_cvt_pk_bf16_f32 %0, %1, %2" : "=v"(r) : "v"(lo), "v"(hi));
    return r;
}

__device__ __forceinline__ void gload_lds16(const u16* g, u16* l) {
    __builtin_amdgcn_global_load_lds((const __attribute__((address_space(1))) void*)g,
                                     (__attribute__((address_space(3))) void*)l, 16, 0, 0);
}

// ---------------- fused prep: RMSNorm (blocks 0..4095) + weight cast (4096..8191)
__global__ __launch_bounds__(256) void prep_kernel(const float* __restrict__ x,
                                                   const float* __restrict__ scale,
                                                   const float* __restrict__ wq,
                                                   const float* __restrict__ wp,
                                                   u16* __restrict__ xn,
                                                   u16* __restrict__ wqb,
                                                   u16* __restrict__ wpb) {
    int bx = blockIdx.x;
    int tid = threadIdx.x;
    if (bx < 4096) {
        int row = bx;
        const float4* xr = reinterpret_cast<const float4*>(x + (size_t)row * E_DIM);
        float4 v = xr[tid];
        float ss = v.x * v.x + v.y * v.y + v.z * v.z + v.w * v.w;
        for (int off = 32; off > 0; off >>= 1) ss += __shfl_xor(ss, off);
        __shared__ float red[4];
        if ((tid & 63) == 0) red[tid >> 6] = ss;
        __syncthreads();
        float total = red[0] + red[1] + red[2] + red[3];
        float rs = rsqrtf(total * (1.0f / E_DIM) + 1e-5f);
        float4 s = reinterpret_cast<const float4*>(scale)[tid];
        u16* o = xn + (size_t)row * E_DIM + tid * 4;
        o[0] = f2bf(v.x * rs * s.x);
        o[1] = f2bf(v.y * rs * s.y);
        o[2] = f2bf(v.z * rs * s.z);
        o[3] = f2bf(v.w * rs * s.w);
    } else {
        const int NQ = (THREE_E * E_DIM) / 4;
        const int NP = (E_DIM * E_DIM) / 4;
        int i = (bx - 4096) * 256 + tid;
        if (i < NQ) {
            float4 v = reinterpret_cast<const float4*>(wq)[i];
            u16* o = wqb + (size_t)i * 4;
            o[0] = f2bf(v.x); o[1] = f2bf(v.y); o[2] = f2bf(v.z); o[3] = f2bf(v.w);
        } else if (i < NQ + NP) {
            int j = i - NQ;
            float4 v = reinterpret_cast<const float4*>(wp)[j];
            u16* o = wpb + (size_t)j * 4;
            o[0] = f2bf(v.x); o[1] = f2bf(v.y); o[2] = f2bf(v.z); o[3] = f2bf(v.w);
        }
    }
}

// ---------------- 2-phase GEMM + T3-minimum async prefetch.
// Per iter: barrier(drains stage(t)); ds_reads(t); barrier(drains reads);
// stage(t+1) into SAME buffer (overlaps MFMA(t)); MFMA(t).
// Stage latency is covered by reads+MFMA instead of exposed at a back-to-back barrier.
// 128xBN tile, BK=64, chunk-XOR LDS swizzle both sides, bijective XCD swizzle.
// C[m][n] = sum_k A[m][k] * Bw[n][k] (bf16 k-contiguous).
template <int BN, bool OUT_BF16>
__global__ __launch_bounds__(256) void gemm_lds_kernel(const u16* __restrict__ A,
                                                       const u16* __restrict__ Bw,
                                                       void* __restrict__ C,
                                                       int N, int K) {
    constexpr int NFR = BN / 32;          // n-frags per wave
    __shared__ u16 As[128 * 64];          // single buffer: 16 KB
    __shared__ u16 Bs[BN * 64];
    int tid = threadIdx.x;
    int lane = tid & 63, wid = tid >> 6;
    int lq = lane & 15, lg = lane >> 4;

    // XCD-aware bijective block swizzle (nwg % 8 == 0 for all uses)
    int gx = gridDim.x;
    int nwg = gx * gridDim.y;
    int orig = blockIdx.y * gx + blockIdx.x;
    int cpx = nwg >> 3;
    int swz = (orig & 7) * cpx + (orig >> 3);
    int bx = swz % gx, by = swz / gx;
    int mblk = by * 128, nblk = bx * BN;

    int srowA = wid * 32 + (lane >> 3);
    int srowB = wid * (BN / 4) + (lane >> 3);
    int csw = ((lane & 7) ^ ((lane >> 3) & 7)) * 8;   // pre-swizzled source chunk
    const u16* gA = A + (size_t)(mblk + srowA) * K + csw;
    const u16* gB = Bw + (size_t)(nblk + srowB) * K + csw;
    u16* lA = As + wid * 2048;
    u16* lB = Bs + wid * (BN / 4) * 64;

    f32x4 acc[4][NFR] = {};
    int m0w = (wid >> 1) * 64;
    int n0w = (wid & 1) * (BN / 2);
    int r7 = lq & 7;
    const int NT = K / 64;

    // prologue: stage tile 0
#pragma unroll
    for (int i = 0; i < 4; ++i) gload_lds16(gA + (size_t)i * 8 * K, lA + i * 512);
#pragma unroll
    for (int i = 0; i < NFR; ++i) gload_lds16(gB + (size_t)i * 8 * K, lB + i * 512);

    for (int t = 0; t < NT; ++t) {
        __syncthreads();   // implicit vmcnt(0): stage(t) landed (all waves)
        short8v af[2][4], bf[2][NFR];
#pragma unroll
        for (int kk = 0; kk < 2; ++kk) {
#pragma unroll
            for (int mi = 0; mi < 4; ++mi)
                af[kk][mi] = *reinterpret_cast<const short8v*>(
                    &As[(m0w + mi * 16 + lq) * 64 + ((kk * 4 + lg) ^ r7) * 8]);
#pragma unroll
            for (int ni = 0; ni < NFR; ++ni)
                bf[kk][ni] = *reinterpret_cast<const short8v*>(
                    &Bs[(n0w + ni * 16 + lq) * 64 + ((kk * 4 + lg) ^ r7) * 8]);
        }
        __syncthreads();   // implicit lgkmcnt(0): all waves done reading tile t
        if (t + 1 < NT) {  // async stage of t+1 overlaps the MFMA cluster below
            int k0 = (t + 1) * 64;
#pragma unroll
            for (int i = 0; i < 4; ++i) gload_lds16(gA + k0 + (size_t)i * 8 * K, lA + i * 512);
#pragma unroll
            for (int i = 0; i < NFR; ++i) gload_lds16(gB + k0 + (size_t)i * 8 * K, lB + i * 512);
        }
        __builtin_amdgcn_sched_barrier(0);   // pin stage issue above the MFMAs
        __builtin_amdgcn_s_setprio(1);
#pragma unroll
        for (int mi = 0; mi < 4; ++mi)
#pragma unroll
            for (int ni = 0; ni < NFR; ++ni) {
                acc[mi][ni] = __builtin_amdgcn_mfma_f32_16x16x32_bf16(af[0][mi], bf[0][ni], acc[mi][ni], 0, 0, 0);
                acc[mi][ni] = __builtin_amdgcn_mfma_f32_16x16x32_bf16(af[1][mi], bf[1][ni], acc[mi][ni], 0, 0, 0);
            }
        __builtin_amdgcn_s_setprio(0);
    }
#pragma unroll
    for (int mi = 0; mi < 4; ++mi) {
#pragma unroll
        for (int ni = 0; ni < NFR; ++ni) {
#pragma unroll
            for (int j = 0; j < 4; ++j) {
                int row = mblk + m0w + mi * 16 + lg * 4 + j;
                int col = nblk + n0w + ni * 16 + lq;
                float val = acc[mi][ni][j];
                if (OUT_BF16)
                    ((u16*)C)[(size_t)row * N + col] = f2bf(val);
                else
                    ((float*)C)[(size_t)row * N + col] = val;
            }
        }
    }
}

// ---------------- attention tile compute (one 16q x 64k tile for one wave)
// Constant-shift softmax (shift-invariant, scores bounded): no max tracking.
// PV via 16x16x16 MFMA: A-frag = own cvt_pk'd P words, zero cross-lane exchange.
template <bool DIAG>
__device__ __forceinline__ void attn_tile(const u16 (*__restrict__ Kt)[72],
                                          const u16 (*__restrict__ Vt)[72],
                                          const short8v* __restrict__ qf,
                                          f32x4* __restrict__ o,
                                          float& l_r,
                                          int lq, int lg, int w4, int kt64, int qg) {
    const float CLOG = 0.18033688011112042f;   // log2(e)/sqrt(64)
    const float MOFF = 11.541560327111707f;    // 8*log2(e)
    int ksmax = DIAG ? w4 : 3;
    f32x4 st[4] = {};
    __builtin_amdgcn_s_setprio(1);
#pragma unroll
    for (int ks = 0; ks < 4; ++ks) {
        if (ks <= ksmax) {
            short8v a0 = *reinterpret_cast<const short8v*>(&Kt[ks * 16 + lq][lg * 8]);
            short8v a1 = *reinterpret_cast<const short8v*>(&Kt[ks * 16 + lq][32 + lg * 8]);
            st[ks] = __builtin_amdgcn_mfma_f32_16x16x32_bf16(a0, qf[0], st[ks], 0, 0, 0);
            st[ks] = __builtin_amdgcn_mfma_f32_16x16x32_bf16(a1, qf[1], st[ks], 0, 0, 0);
        }
    }
    __builtin_amdgcn_s_setprio(0);
    float p[4][4];
    float psum = 0.f;
#pragma unroll
    for (int ks = 0; ks < 4; ++ks)
#pragma unroll
        for (int j = 0; j < 4; ++j) {
            float v = st[ks][j];
            if (DIAG) {
                int kg = kt64 + ks * 16 + lg * 4 + j;
                v = (ks <= ksmax && kg <= qg) ? v : -INFINITY;
            }
            float pv = exp2f(fmaf(v, CLOG, -MOFF));
            p[ks][j] = pv;
            psum += pv;
        }
    l_r += psum;
    union { u32 w2[2]; short4v v; } pa[4];
#pragma unroll
    for (int ks = 0; ks < 4; ++ks) {
        pa[ks].w2[0] = cvt_pk_bf16(p[ks][0], p[ks][1]);
        pa[ks].w2[1] = cvt_pk_bf16(p[ks][2], p[ks][3]);
    }
    __builtin_amdgcn_s_setprio(1);
#pragma unroll
    for (int ni = 0; ni < 4; ++ni) {
        int d = ni * 16 + lq;
        int sw = ((d >> 3) & 7) << 3;
        const u16* vrow = Vt[d];
#pragma unroll
        for (int ks = 0; ks < 4; ++ks) {
            if (ks <= ksmax) {
                short4v vb = *reinterpret_cast<const short4v*>(&vrow[(ks * 16 + lg * 4) ^ sw]);
                o[ni] = __builtin_amdgcn_mfma_f32_16x16x16bf16_1k(pa[ks].v, vb, o[ni], 0, 0, 0);
            }
        }
    }
    __builtin_amdgcn_s_setprio(0);
}

// ---------------- flash attention, causal, balanced dual q-tile blocks, 8 waves.
// grid (8, 64), 512 threads. Waves 0-3: lo qblk tiles; waves 4-7: hi qblk tiles.
__global__ __launch_bounds__(512) void attn_kernel(const u16* __restrict__ qkv,
                                                   u16* __restrict__ out) {
    int tid = threadIdx.x;
    int lane = tid & 63, wid = tid >> 6;
    int lq = lane & 15, lg = lane >> 4;
    int w4 = wid & 3;
    bool is_hi = wid >= 4;
    int bh = blockIdx.y;
    int b = bh >> 4, h = bh & 15;
    int qlo_blk = blockIdx.x;
    int qhi_blk = 15 - qlo_blk;
    int myblk = is_hi ? qhi_blk : qlo_blk;
    int qt = myblk * 64 + w4 * 16;

    const u16* base = qkv + (size_t)b * T_SEQ * THREE_E;
    const u16* Qb = base + h * HD;
    const u16* Kb = base + E_DIM + h * HD;

    __shared__ __align__(16) u16 Kt[2][64][72];
    __shared__ __align__(16) u16 Vt[2][64][72];

    short8v qf[2];
    {
        const u16* qr = Qb + (size_t)(qt + lq) * THREE_E + lg * 8;
        qf[0] = *reinterpret_cast<const short8v*>(qr);
        qf[1] = *reinterpret_cast<const short8v*>(qr + 32);
    }
    f32x4 o[4] = {};
    float l_r = 0.f;
    int qg = qt + lq;

    int row_s = tid >> 3, c8 = tid & 7;   // 512 threads -> rows 0..63, one 16B each
    short8v kreg, vreg;

    // prologue: stage tile 0 into buf0, prefetch tile 1
    {
        const u16* src = Kb + (size_t)row_s * THREE_E + c8 * 8;
        kreg = *reinterpret_cast<const short8v*>(src);
        vreg = *reinterpret_cast<const short8v*>(src + E_DIM);
    }
    {
        *reinterpret_cast<short8v*>(&Kt[0][row_s][c8 * 8]) = kreg;
        int rs = row_s ^ (c8 << 3);
#pragma unroll
        for (int e = 0; e < 8; ++e) Vt[0][c8 * 8 + e][rs] = (u16)vreg[e];
    }
    if (qhi_blk >= 1) {
        const u16* src = Kb + (size_t)(64 + row_s) * THREE_E + c8 * 8;
        kreg = *reinterpret_cast<const short8v*>(src);
        vreg = *reinterpret_cast<const short8v*>(src + E_DIM);
    }
    __syncthreads();

    for (int kt = 0; kt <= qhi_blk; ++kt) {
        int cur = kt & 1;
        if (kt < qhi_blk) {
            *reinterpret_cast<short8v*>(&Kt[cur ^ 1][row_s][c8 * 8]) = kreg;
            int rs = row_s ^ (c8 << 3);
#pragma unroll
            for (int e = 0; e < 8; ++e) Vt[cur ^ 1][c8 * 8 + e][rs] = (u16)vreg[e];
            if (kt + 1 < qhi_blk) {
                const u16* src = Kb + (size_t)((kt + 2) * 64 + row_s) * THREE_E + c8 * 8;
                kreg = *reinterpret_cast<const short8v*>(src);
                vreg = *reinterpret_cast<const short8v*>(src + E_DIM);
            }
        }
        if (is_hi) {
            if (kt < qhi_blk)
                attn_tile<false>(Kt[cur], Vt[cur], qf, o, l_r, lq, lg, w4, kt * 64, qg);
            else
                attn_tile<true>(Kt[cur], Vt[cur], qf, o, l_r, lq, lg, w4, kt * 64, qg);
        } else {
            if (kt < qlo_blk)
                attn_tile<false>(Kt[cur], Vt[cur], qf, o, l_r, lq, lg, w4, kt * 64, qg);
            else if (kt == qlo_blk)
                attn_tile<true>(Kt[cur], Vt[cur], qf, o, l_r, lq, lg, w4, kt * 64, qg);
        }
        __syncthreads();
    }
    // epilogue: reduce l across the 4 lanes sharing lq, normalize, store bf16
    float lf = l_r;
    lf += __shfl_xor(lf, 16); lf += __shfl_xor(lf, 32);
#pragma unroll
    for (int j = 0; j < 4; ++j) {
        float linv = 1.0f / __shfl(lf, lg * 4 + j);
        size_t row = (size_t)b * T_SEQ + qt + lg * 4 + j;
#pragma unroll
        for (int ni = 0; ni < 4; ++ni)
            out[row * E_DIM + h * HD + ni * 16 + lq] = f2bf(o[ni][j] * linv);
    }
}

// ---------------- launch
extern "C" void kernel_launch(void* const* d_in, const int* in_sizes, int n_in,
                              void* d_out, int out_size, void* d_ws, size_t ws_size,
                              hipStream_t stream) {
    const float* x = (const float*)d_in[0];
    const float* scale = (const float*)d_in[1];
    const float* w_qkv = (const float*)d_in[2];
    const float* w_proj = (const float*)d_in[3];
    float* out = (float*)d_out;

    char* ws = (char*)d_ws;
    u16* xn   = (u16*)(ws);                    // 8 MB
    u16* wqb  = (u16*)(ws + (8ull << 20));     // 6 MB
    u16* wpb  = (u16*)(ws + (14ull << 20));    // 2 MB
    u16* qkv  = (u16*)(ws + (16ull << 20));    // 24 MB
    u16* aout = (u16*)(ws + (40ull << 20));    // 8 MB

    prep_kernel<<<dim3(8192), dim3(256), 0, stream>>>(x, scale, w_qkv, w_proj, xn, wqb, wpb);
    gemm_lds_kernel<128, true><<<dim3(THREE_E / 128, NTOK / 128), dim3(256), 0, stream>>>(
        xn, wqb, (void*)qkv, THREE_E, E_DIM);
    attn_kernel<<<dim3(8, B_SZ * NH), dim3(512), 0, stream>>>(qkv, aout);
    gemm_lds_kernel<64, false><<<dim3(E_DIM / 64, NTOK / 128), dim3(256), 0, stream>>>(
        aout, wpb, (void*)out, E_DIM, E_DIM);
}